// Round 5
// baseline (209.990 us; speedup 1.0000x reference)
//
#include <hip/hip_runtime.h>
#include <math.h>

// Problem constants
#define NB 32
#define CI 64
#define CO 64
#define CA 16
#define NK 4
#define HH 128
#define WW 128
#define EPSBN 1e-5f

typedef __bf16 bf16x8 __attribute__((ext_vector_type(8)));
typedef float f32x4 __attribute__((ext_vector_type(4)));

__device__ inline unsigned short f2bf(float f) {
    union { float f; unsigned u; } c; c.f = f;
    return (unsigned short)((c.u + 0x7fffu + ((c.u >> 16) & 1u)) >> 16);
}

// Workspace layout (float offsets). Total = 17,440,768 floats = 69.8 MB
// (r4 ran the 70.5 MB path, so ws_size is sufficient).
#define WS_CHA   0              // 2048
#define WS_FA    2048           // 2048
#define WS_KA    4096           // 128
#define WS_SP    4224           // 288
#define WS_PART  8192           // 32*64*32 = 65536
#define WS_W2T   73728          // 1179648 ushorts = 589824 float slots
#define WS_XT    663552         // 33554432 ushorts = 16777216 float slots

// ===========================================================================
// 1) convert+pool: x[b][ci][h][w] f32 -> xt[b][h][w][ci] bf16 (NHWC),
//    plus per-(b,ci,hgroup) partial sums. Block = (hg of 4 rows, b).
//    Reads fully coalesced (contiguous 2KB per wave); LDS transpose; writes
//    64B-per-(w,ci-half) units.
// ===========================================================================
__global__ __launch_bounds__(256) void convert_pool2(const float* __restrict__ x,
                                                     unsigned short* __restrict__ xt,
                                                     float* __restrict__ partial) {
    __shared__ unsigned short tl[4 * 128 * 36];   // [r][w][32ci + 4 pad] halfwords
    __shared__ float red[64 * 2];
    const int tid = threadIdx.x;
    const int hg = blockIdx.x;       // 0..31
    const int b  = blockIdx.y;
    const int h0 = hg * 4;
    const int wq    = tid & 31;      // 16B window within row
    const int r     = (tid >> 5) & 3;
    const int cipar = tid >> 7;      // 0/1
    const int wv    = tid >> 6;

    #pragma unroll 1
    for (int half = 0; half < 2; ++half) {
        if (half) __syncthreads();
        #pragma unroll
        for (int ii = 0; ii < 16; ++ii) {
            const int ci = half * 32 + ii * 2 + cipar;
            const float4 a = *(const float4*)(x + ((size_t)(b * CI + ci) * HH + h0 + r) * WW + wq * 4);
            float s = a.x + a.y + a.z + a.w;
            #pragma unroll
            for (int off = 32; off > 0; off >>= 1) s += __shfl_down(s, off);
            if ((tid & 63) == 0) red[ci * 2 + (wv & 1)] = s;
            const float av[4] = {a.x, a.y, a.z, a.w};
            #pragma unroll
            for (int e = 0; e < 4; ++e)
                tl[(r * 128 + wq * 4 + e) * 36 + ii * 2 + cipar] = f2bf(av[e]);
        }
        __syncthreads();
        // write phase: 512 units of 64B (4r x 128w), 2 iters
        #pragma unroll
        for (int it = 0; it < 2; ++it) {
            const int u = it * 256 + tid;
            const int wr = u >> 7, w = u & 127;
            const unsigned short* sx = tl + (wr * 128 + w) * 36;
            unsigned q[16];
            #pragma unroll
            for (int j = 0; j < 16; ++j) q[j] = *(const unsigned*)(sx + 2 * j);
            unsigned short* dst = xt + ((size_t)(b * HH + h0 + wr) * WW + w) * CI + half * 32;
            #pragma unroll
            for (int j = 0; j < 4; ++j)
                ((uint4*)dst)[j] = make_uint4(q[4*j], q[4*j+1], q[4*j+2], q[4*j+3]);
        }
    }
    if (tid < 64)
        partial[((size_t)b * CI + tid) * 32 + hg] = red[tid * 2] + red[tid * 2 + 1];
}

// ===========================================================================
// 2) attention: fold pool reduction + trunk + 4 heads. 1 block, 512 threads.
// ===========================================================================
__global__ __launch_bounds__(512) void attn3(
    const float* __restrict__ partial, const float* __restrict__ prep_w,
    const float* __restrict__ bn_g, const float* __restrict__ bn_b,
    const float* __restrict__ bn_m, const float* __restrict__ bn_v,
    const float* __restrict__ fc_sp_w, const float* __restrict__ fc_sp_b,
    const float* __restrict__ fc_ch_w, const float* __restrict__ fc_ch_b,
    const float* __restrict__ fc_f_w,  const float* __restrict__ fc_f_b,
    const float* __restrict__ fc_k_w,  const float* __restrict__ fc_k_b,
    float* __restrict__ sp, float* __restrict__ cha,
    float* __restrict__ fa, float* __restrict__ ka) {
    __shared__ float pooled_s[NB * CI];
    __shared__ float att_s[NB * CA];
    const int tid = threadIdx.x;
    const float scale = 1.f / (HH * WW);
    #pragma unroll
    for (int i = 0; i < 4; ++i) {
        const int e = tid + 512 * i;
        const float* pp = partial + (size_t)e * 32;
        float s = 0.f;
        #pragma unroll
        for (int j = 0; j < 32; ++j) s += pp[j];
        pooled_s[e] = s;
    }
    __syncthreads();
    const int b = tid >> 4, a = tid & 15;
    {
        float s = 0.f;
        const float* pv = pooled_s + b * CI;
        #pragma unroll
        for (int c = 0; c < CI; ++c) s += pv[c] * prep_w[a * CI + c];
        s = (s * scale - bn_m[a]) * rsqrtf(bn_v[a] + EPSBN) * bn_g[a] + bn_b[a];
        att_s[b * CA + a] = fmaxf(s, 0.f);
    }
    __syncthreads();
    float av[CA];
    #pragma unroll
    for (int i = 0; i < CA; ++i) av[i] = att_s[b * CA + i];

    const int j = a;
    if (j < 9) {
        float s = fc_sp_b[j];
        #pragma unroll
        for (int i = 0; i < CA; ++i) s += av[i] * fc_sp_w[j * CA + i];
        sp[b * 9 + j] = 1.f / (1.f + expf(-s));
    }
    #pragma unroll
    for (int t = 0; t < 4; ++t) {
        const int c = j * 4 + t;
        float s1 = fc_ch_b[c], s2 = fc_f_b[c];
        #pragma unroll
        for (int i = 0; i < CA; ++i) {
            s1 += av[i] * fc_ch_w[c * CA + i];
            s2 += av[i] * fc_f_w[c * CA + i];
        }
        cha[b * CI + c] = 1.f / (1.f + expf(-s1));
        fa[b * CO + c]  = 1.f / (1.f + expf(-s2));
    }
    if (j == 0) {
        float kv[NK], m = -1e30f;
        #pragma unroll
        for (int k = 0; k < NK; ++k) {
            float s = fc_k_b[k];
            #pragma unroll
            for (int i = 0; i < CA; ++i) s += av[i] * fc_k_w[k * CA + i];
            kv[k] = s; m = fmaxf(m, s);
        }
        float den = 0.f;
        #pragma unroll
        for (int k = 0; k < NK; ++k) { kv[k] = expf(kv[k] - m); den += kv[k]; }
        #pragma unroll
        for (int k = 0; k < NK; ++k) ka[b * NK + k] = kv[k] / den;
    }
}

// ===========================================================================
// 3) folded weights w2t[b][tap][o][i] bf16. Block = (b, o-quad); lanes = i
//    so writes are full 128B lines; reads are 36B/lane dense (L1/L2-hot).
// ===========================================================================
__global__ __launch_bounds__(256) void w2t2(const float* __restrict__ kernels,
                                            const float* __restrict__ sp,
                                            const float* __restrict__ cha,
                                            const float* __restrict__ fa,
                                            const float* __restrict__ ka,
                                            unsigned short* __restrict__ w2t) {
    const int bid = blockIdx.x;              // 32*16
    const int b  = bid >> 4;
    const int o  = (bid & 15) * 4 + (threadIdx.x >> 6);
    const int i  = threadIdx.x & 63;
    float kw[NK][9];
    #pragma unroll
    for (int k = 0; k < NK; ++k) {
        const float* kp = kernels + ((size_t)(k * CO + o) * CI + i) * 9;
        #pragma unroll
        for (int t = 0; t < 9; ++t) kw[k][t] = kp[t];
    }
    float kav[NK];
    #pragma unroll
    for (int k = 0; k < NK; ++k) kav[k] = ka[b * NK + k];
    const float base = cha[b * CI + i] * fa[b * CO + o];
    #pragma unroll
    for (int tap = 0; tap < 9; ++tap) {
        float s = 0.f;
        #pragma unroll
        for (int k = 0; k < NK; ++k) s += kav[k] * kw[k][tap];
        w2t[((size_t)(b * 9 + tap) * CO + o) * CI + i] = f2bf(s * sp[b * 9 + tap] * base);
    }
}

// ===========================================================================
// 4) LDS-free conv via mfma_f32_16x16x32_bf16 (sector-perfect fragments).
//    Block = (b, hg, colpair): 4 waves = (colg within pair, cohalf).
//    Wave tile: 32co x 32cols x 4rows; acc[og2][cg2][t4] f32x4.
// ===========================================================================
__global__ __launch_bounds__(256, 2) void conv16(const unsigned short* __restrict__ xt,
                                                 const unsigned short* __restrict__ w2t,
                                                 float* __restrict__ out) {
    const int orig = blockIdx.x;
    const int bid  = (orig & 7) * 256 + (orig >> 3);   // XCD swizzle (bijective, 2048=8*256)
    const int b   = bid >> 6;
    const int rem = bid & 63;
    const int hg  = rem >> 1;
    const int cp  = rem & 1;
    const int wv     = threadIdx.x >> 6;
    const int colg   = cp * 2 + (wv >> 1);
    const int cohalf = wv & 1;
    const int lane = threadIdx.x & 63;
    const int cl = lane & 15;        // col-in-16 / o-in-16
    const int kq = lane >> 4;        // k-quarter (8 ci each)
    const int h0 = hg * 4;
    const int w0 = colg * 32;

    const unsigned short* xb  = xt + (size_t)b * (HH * WW * CI);
    const unsigned short* w2b = w2t + (size_t)b * (9 * 4096)
                              + (size_t)(cohalf * 32) * 64 + kq * 8;

    f32x4 acc[2][2][4];
    #pragma unroll
    for (int og = 0; og < 2; ++og)
        #pragma unroll
        for (int cg = 0; cg < 2; ++cg)
            #pragma unroll
            for (int t = 0; t < 4; ++t)
                #pragma unroll
                for (int e = 0; e < 4; ++e) acc[og][cg][t][e] = 0.f;

    #pragma unroll
    for (int v = 0; v < 3; ++v) {
        #pragma unroll
        for (int ks = 0; ks < 2; ++ks) {
            bf16x8 A[3][2];
            #pragma unroll
            for (int u = 0; u < 3; ++u)
                #pragma unroll
                for (int og = 0; og < 2; ++og)
                    A[u][og] = *(const bf16x8*)(w2b + (size_t)(u * 3 + v) * 4096
                                                + (og * 16 + cl) * 64 + ks * 32);
            #pragma unroll
            for (int cg = 0; cg < 2; ++cg) {
                const int col = w0 + cg * 16 + cl + v - 1;
                const bool cok = (unsigned)col < (unsigned)WW;
                const unsigned short* bp = xb + (size_t)col * CI + ks * 32 + kq * 8;
                bf16x8 Bf[6];
                #pragma unroll
                for (int r = 0; r < 6; ++r) {
                    const int hh = h0 - 1 + r;
                    union { uint4 u4; bf16x8 v8; } z; z.u4 = make_uint4(0u, 0u, 0u, 0u);
                    if (cok && (unsigned)hh < (unsigned)HH)
                        z.v8 = *(const bf16x8*)(bp + (size_t)hh * (WW * CI));
                    Bf[r] = z.v8;
                }
                #pragma unroll
                for (int u = 0; u < 3; ++u)
                    #pragma unroll
                    for (int og = 0; og < 2; ++og)
                        #pragma unroll
                        for (int t = 0; t < 4; ++t)
                            acc[og][cg][t] = __builtin_amdgcn_mfma_f32_16x16x32_bf16(
                                A[u][og], Bf[t + u], acc[og][cg][t], 0, 0, 0);
            }
        }
    }

    // epilogue: C/D row = kq*4 + reg (co within 16), col = cl
    #pragma unroll
    for (int og = 0; og < 2; ++og)
        #pragma unroll
        for (int cg = 0; cg < 2; ++cg)
            #pragma unroll
            for (int t = 0; t < 4; ++t) {
                #pragma unroll
                for (int rg = 0; rg < 4; ++rg) {
                    const int co = cohalf * 32 + og * 16 + kq * 4 + rg;
                    out[((size_t)(b * CO + co) * HH + h0 + t) * WW + w0 + cg * 16 + cl]
                        = acc[og][cg][t][rg];
                }
            }
}

// ===========================================================================
extern "C" void kernel_launch(void* const* d_in, const int* in_sizes, int n_in,
                              void* d_out, int out_size, void* d_ws, size_t ws_size,
                              hipStream_t stream) {
    const float* x        = (const float*)d_in[0];
    const float* prep_w   = (const float*)d_in[1];
    const float* bn_g     = (const float*)d_in[2];
    const float* bn_b     = (const float*)d_in[3];
    const float* bn_m     = (const float*)d_in[4];
    const float* bn_v     = (const float*)d_in[5];
    const float* fc_sp_w  = (const float*)d_in[6];
    const float* fc_sp_b  = (const float*)d_in[7];
    const float* fc_ch_w  = (const float*)d_in[8];
    const float* fc_ch_b  = (const float*)d_in[9];
    const float* fc_f_w   = (const float*)d_in[10];
    const float* fc_f_b   = (const float*)d_in[11];
    const float* fc_k_w   = (const float*)d_in[12];
    const float* fc_k_b   = (const float*)d_in[13];
    const float* kernels  = (const float*)d_in[14];
    float* out = (float*)d_out;
    float* ws  = (float*)d_ws;

    float* cha     = ws + WS_CHA;
    float* fa      = ws + WS_FA;
    float* ka      = ws + WS_KA;
    float* sp      = ws + WS_SP;
    float* partial = ws + WS_PART;
    unsigned short* w2t = (unsigned short*)(ws + WS_W2T);
    unsigned short* xt  = (unsigned short*)(ws + WS_XT);

    convert_pool2<<<dim3(32, NB), 256, 0, stream>>>(x, xt, partial);
    attn3<<<1, 512, 0, stream>>>(partial, prep_w, bn_g, bn_b, bn_m, bn_v,
                                 fc_sp_w, fc_sp_b, fc_ch_w, fc_ch_b,
                                 fc_f_w, fc_f_b, fc_k_w, fc_k_b,
                                 sp, cha, fa, ka);
    w2t2<<<NB * 16, 256, 0, stream>>>(kernels, sp, cha, fa, ka, w2t);
    conv16<<<2048, 256, 0, stream>>>(xt, w2t, out);
}

// Round 6
// 205.311 us; speedup vs baseline: 1.0228x; 1.0228x over previous
//
#include <hip/hip_runtime.h>
#include <math.h>

// Problem constants
#define NB 32
#define CI 64
#define CO 64
#define CA 16
#define NK 4
#define HH 128
#define WW 128
#define EPSBN 1e-5f

typedef __bf16 bf16x8 __attribute__((ext_vector_type(8)));
typedef float f32x4 __attribute__((ext_vector_type(4)));

__device__ inline unsigned short f2bf(float f) {
    union { float f; unsigned u; } c; c.f = f;
    return (unsigned short)((c.u + 0x7fffu + ((c.u >> 16) & 1u)) >> 16);
}

__device__ inline void gload_lds16(const void* g, void* l) {
    __builtin_amdgcn_global_load_lds(
        (const __attribute__((address_space(1))) unsigned int*)g,
        (__attribute__((address_space(3))) unsigned int*)l, 16, 0, 0);
}

// Workspace layout (float offsets). Total 17,637,376 floats = 70.5 MB (r4 proven).
#define WS_ZERO  0              // 64 (zero page for OOB redirect)
#define WS_CHA   64             // 2048
#define WS_FA    2112           // 2048
#define WS_KA    4160           // 128
#define WS_SP    4288           // 288
#define WS_PART  8192           // 32*64*128 = 262144
#define WS_W2T   270336         // 1179648 ushorts = 589824 float slots
#define WS_XT    860160         // 33554432 ushorts = 16777216 float slots

// ===========================================================================
// 1) Register transpose: x[b][ci][h][w] f32 -> xt[b][h][w][ci] bf16 (NHWC),
//    + per-(b,ci,h) pool partials. Block = (h, b), 256 thr = 4 waves
//    (ci-half x w-half). Wave loads 32 rows of 256B (coalesced); lane j then
//    holds all 32 ci for w=j -> pack -> 64B/lane stores. Pool via f32 LDS.
// ===========================================================================
__global__ __launch_bounds__(256) void transpose_pool(const float* __restrict__ x,
                                                      unsigned short* __restrict__ xt,
                                                      float* __restrict__ partial,
                                                      float* __restrict__ zeros) {
    __shared__ float vs[64 * 129];
    __shared__ float red[64 * 4];
    const int tid = threadIdx.x;
    const int h = blockIdx.x;
    const int b = blockIdx.y;
    const int lane = tid & 63;
    const int wv  = tid >> 6;
    const int cih = wv & 1;
    const int wh  = wv >> 1;
    const int w = wh * 64 + lane;

    if (h == 0 && b == 0 && tid < 64) zeros[tid] = 0.f;   // zero page for conv

    float vals[32];
    const float* xp = x + ((size_t)(b * CI + cih * 32) * HH + h) * WW + w;
    #pragma unroll
    for (int i = 0; i < 32; ++i) vals[i] = xp[(size_t)i * (HH * WW)];

    #pragma unroll
    for (int i = 0; i < 32; ++i) vs[(cih * 32 + i) * 129 + w] = vals[i];

    // pack to bf16 and store NHWC (64B per lane)
    unsigned q[16];
    #pragma unroll
    for (int i = 0; i < 16; ++i)
        q[i] = (unsigned)f2bf(vals[2 * i]) | ((unsigned)f2bf(vals[2 * i + 1]) << 16);
    unsigned short* dst = xt + ((size_t)(b * HH + h) * WW + w) * CI + cih * 32;
    #pragma unroll
    for (int j = 0; j < 4; ++j)
        ((uint4*)dst)[j] = make_uint4(q[4 * j], q[4 * j + 1], q[4 * j + 2], q[4 * j + 3]);

    __syncthreads();
    {
        const int ci = tid & 63, qd = tid >> 6;
        float s = 0.f;
        #pragma unroll
        for (int e = 0; e < 32; ++e) s += vs[ci * 129 + qd * 32 + e];
        red[ci * 4 + qd] = s;
    }
    __syncthreads();
    if (tid < 64)
        partial[((size_t)b * CI + tid) * HH + h] =
            red[tid * 4] + red[tid * 4 + 1] + red[tid * 4 + 2] + red[tid * 4 + 3];
}

// ===========================================================================
// 2) attention: reduce partials (128 h) + trunk + 4 heads. 1 block, 512 thr.
// ===========================================================================
__global__ __launch_bounds__(512) void attn3(
    const float* __restrict__ partial, const float* __restrict__ prep_w,
    const float* __restrict__ bn_g, const float* __restrict__ bn_b,
    const float* __restrict__ bn_m, const float* __restrict__ bn_v,
    const float* __restrict__ fc_sp_w, const float* __restrict__ fc_sp_b,
    const float* __restrict__ fc_ch_w, const float* __restrict__ fc_ch_b,
    const float* __restrict__ fc_f_w,  const float* __restrict__ fc_f_b,
    const float* __restrict__ fc_k_w,  const float* __restrict__ fc_k_b,
    float* __restrict__ sp, float* __restrict__ cha,
    float* __restrict__ fa, float* __restrict__ ka) {
    __shared__ float pooled_s[NB * CI];
    __shared__ float att_s[NB * CA];
    const int tid = threadIdx.x;
    const float scale = 1.f / (HH * WW);
    #pragma unroll
    for (int i = 0; i < 4; ++i) {
        const int e = tid + 512 * i;
        const float4* pp = (const float4*)(partial + (size_t)e * HH);
        float s = 0.f;
        #pragma unroll
        for (int j = 0; j < 32; ++j) { float4 v = pp[j]; s += v.x + v.y + v.z + v.w; }
        pooled_s[e] = s;
    }
    __syncthreads();
    const int b = tid >> 4, a = tid & 15;
    {
        float s = 0.f;
        const float* pv = pooled_s + b * CI;
        #pragma unroll
        for (int c = 0; c < CI; ++c) s += pv[c] * prep_w[a * CI + c];
        s = (s * scale - bn_m[a]) * rsqrtf(bn_v[a] + EPSBN) * bn_g[a] + bn_b[a];
        att_s[b * CA + a] = fmaxf(s, 0.f);
    }
    __syncthreads();
    float av[CA];
    #pragma unroll
    for (int i = 0; i < CA; ++i) av[i] = att_s[b * CA + i];

    const int j = a;
    if (j < 9) {
        float s = fc_sp_b[j];
        #pragma unroll
        for (int i = 0; i < CA; ++i) s += av[i] * fc_sp_w[j * CA + i];
        sp[b * 9 + j] = 1.f / (1.f + expf(-s));
    }
    #pragma unroll
    for (int t = 0; t < 4; ++t) {
        const int c = j * 4 + t;
        float s1 = fc_ch_b[c], s2 = fc_f_b[c];
        #pragma unroll
        for (int i = 0; i < CA; ++i) {
            s1 += av[i] * fc_ch_w[c * CA + i];
            s2 += av[i] * fc_f_w[c * CA + i];
        }
        cha[b * CI + c] = 1.f / (1.f + expf(-s1));
        fa[b * CO + c]  = 1.f / (1.f + expf(-s2));
    }
    if (j == 0) {
        float kv[NK], m = -1e30f;
        #pragma unroll
        for (int k = 0; k < NK; ++k) {
            float s = fc_k_b[k];
            #pragma unroll
            for (int i = 0; i < CA; ++i) s += av[i] * fc_k_w[k * CA + i];
            kv[k] = s; m = fmaxf(m, s);
        }
        float den = 0.f;
        #pragma unroll
        for (int k = 0; k < NK; ++k) { kv[k] = expf(kv[k] - m); den += kv[k]; }
        #pragma unroll
        for (int k = 0; k < NK; ++k) ka[b * NK + k] = kv[k] / den;
    }
}

// ===========================================================================
// 3) folded weights w2t[b][tap][o][i] bf16 (lanes = i: 128B-line writes)
// ===========================================================================
__global__ __launch_bounds__(256) void w2t2(const float* __restrict__ kernels,
                                            const float* __restrict__ sp,
                                            const float* __restrict__ cha,
                                            const float* __restrict__ fa,
                                            const float* __restrict__ ka,
                                            unsigned short* __restrict__ w2t) {
    const int bid = blockIdx.x;              // 32*16
    const int b  = bid >> 4;
    const int o  = (bid & 15) * 4 + (threadIdx.x >> 6);
    const int i  = threadIdx.x & 63;
    float kw[NK][9];
    #pragma unroll
    for (int k = 0; k < NK; ++k) {
        const float* kp = kernels + ((size_t)(k * CO + o) * CI + i) * 9;
        #pragma unroll
        for (int t = 0; t < 9; ++t) kw[k][t] = kp[t];
    }
    float kav[NK];
    #pragma unroll
    for (int k = 0; k < NK; ++k) kav[k] = ka[b * NK + k];
    const float base = cha[b * CI + i] * fa[b * CO + o];
    #pragma unroll
    for (int tap = 0; tap < 9; ++tap) {
        float s = 0.f;
        #pragma unroll
        for (int k = 0; k < NK; ++k) s += kav[k] * kw[k][tap];
        w2t[((size_t)(b * 9 + tap) * CO + o) * CI + i] = f2bf(s * sp[b * 9 + tap] * base);
    }
}

// ===========================================================================
// 4) LDS-staged conv (mfma_f32_16x16x32_bf16). Block = 64co x 64col x 4row,
//    512 thr = 8 waves (cohalf x colq). Whole K staged once: 6r x 66c x 64ci
//    bf16 (50688B) via ~50 global_load_lds dwordx4 (zero-page redirect for
//    halo/OOB lanes; oct-XOR swizzle baked into the *source* address).
//    LDS unit (row*528 + col*8 + s) holds global oct (s ^ (col&7)) of (row,col).
// ===========================================================================
__global__ __launch_bounds__(512, 4) void conv_lds(const unsigned short* __restrict__ xt,
                                                   const unsigned short* __restrict__ w2t,
                                                   const unsigned short* __restrict__ zeros,
                                                   float* __restrict__ out) {
    __shared__ __align__(16) unsigned char xs[51200];   // 50 chunks x 1024B (pad incl.)
    const int tid  = threadIdx.x;
    const int lane = tid & 63;
    const int wv   = tid >> 6;
    const int orig = blockIdx.x;
    const int bid  = (orig & 7) * 256 + (orig >> 3);    // XCD swizzle (bijective)
    const int b   = bid >> 6;
    const int rem = bid & 63;
    const int hg  = rem >> 1;
    const int cg2 = rem & 1;
    const int h0 = hg * 4;
    const int w0 = cg2 * 64;

    const unsigned short* xb = xt + (size_t)b * (HH * WW * CI);

    // ---- stage: 3168 16B-units (+pad), all loads in flight before barrier
    for (int chunk = wv; chunk < 50; chunk += 8) {
        const int unit = (chunk << 6) + lane;
        const int row  = (int)((unsigned)unit / 528u);
        const int rr   = unit - row * 528;
        const int col  = rr >> 3;
        const int q    = rr & 7;
        const int hh = h0 - 1 + row;
        const int wc = w0 - 1 + col;
        const unsigned short* g = zeros;
        if (unit < 3168 && (unsigned)hh < (unsigned)HH && (unsigned)wc < (unsigned)WW)
            g = xb + (((size_t)hh << 7) + (size_t)wc) * 64 + ((q ^ (col & 7)) << 3);
        gload_lds16(g, xs + (chunk << 10));
    }
    __syncthreads();

    // ---- compute: 144 MFMA/wave fed by 36 ds_read_b128 + 36 A loads (L2-hot)
    const int cl = lane & 15;        // pixel col in 16 / o in 16
    const int kq = lane >> 4;        // k-quarter (8 ci)
    const int cohalf = wv & 1;
    const int colq   = wv >> 1;      // 0..3

    const unsigned short* w2b = w2t + (size_t)b * (9 * 4096)
                              + (size_t)(cohalf * 32) * 64 + kq * 8;

    f32x4 acc[2][4];
    #pragma unroll
    for (int og = 0; og < 2; ++og)
        #pragma unroll
        for (int t = 0; t < 4; ++t)
            #pragma unroll
            for (int e = 0; e < 4; ++e) acc[og][t][e] = 0.f;

    #pragma unroll
    for (int ks = 0; ks < 2; ++ks) {
        #pragma unroll
        for (int v = 0; v < 3; ++v) {
            const int lcol = colq * 16 + cl + v;            // LDS col 0..65
            const int sw = ((ks << 2) + kq) ^ (lcol & 7);   // swizzled oct slot
            const unsigned char* bp = xs + (((lcol << 3) + sw) << 4);
            bf16x8 Bf[6];
            #pragma unroll
            for (int r = 0; r < 6; ++r)
                Bf[r] = *(const bf16x8*)(bp + r * 8448);
            #pragma unroll
            for (int u = 0; u < 3; ++u) {
                const unsigned short* wp = w2b + (size_t)(u * 3 + v) * 4096 + ks * 32;
                const bf16x8 A0 = *(const bf16x8*)(wp + cl * 64);
                const bf16x8 A1 = *(const bf16x8*)(wp + (16 + cl) * 64);
                #pragma unroll
                for (int t = 0; t < 4; ++t)
                    acc[0][t] = __builtin_amdgcn_mfma_f32_16x16x32_bf16(A0, Bf[t + u], acc[0][t], 0, 0, 0);
                #pragma unroll
                for (int t = 0; t < 4; ++t)
                    acc[1][t] = __builtin_amdgcn_mfma_f32_16x16x32_bf16(A1, Bf[t + u], acc[1][t], 0, 0, 0);
            }
        }
    }

    // ---- epilogue: C/D row (co-in-16) = kq*4 + rg, col = cl
    #pragma unroll
    for (int og = 0; og < 2; ++og)
        #pragma unroll
        for (int t = 0; t < 4; ++t) {
            float* op = out + ((size_t)(b * CO + cohalf * 32 + og * 16 + kq * 4) * HH + h0 + t) * WW
                      + w0 + colq * 16 + cl;
            #pragma unroll
            for (int rg = 0; rg < 4; ++rg)
                op[(size_t)rg * (HH * WW)] = acc[og][t][rg];
        }
}

// ===========================================================================
extern "C" void kernel_launch(void* const* d_in, const int* in_sizes, int n_in,
                              void* d_out, int out_size, void* d_ws, size_t ws_size,
                              hipStream_t stream) {
    const float* x        = (const float*)d_in[0];
    const float* prep_w   = (const float*)d_in[1];
    const float* bn_g     = (const float*)d_in[2];
    const float* bn_b     = (const float*)d_in[3];
    const float* bn_m     = (const float*)d_in[4];
    const float* bn_v     = (const float*)d_in[5];
    const float* fc_sp_w  = (const float*)d_in[6];
    const float* fc_sp_b  = (const float*)d_in[7];
    const float* fc_ch_w  = (const float*)d_in[8];
    const float* fc_ch_b  = (const float*)d_in[9];
    const float* fc_f_w   = (const float*)d_in[10];
    const float* fc_f_b   = (const float*)d_in[11];
    const float* fc_k_w   = (const float*)d_in[12];
    const float* fc_k_b   = (const float*)d_in[13];
    const float* kernels  = (const float*)d_in[14];
    float* out = (float*)d_out;
    float* ws  = (float*)d_ws;

    float* zeros   = ws + WS_ZERO;
    float* cha     = ws + WS_CHA;
    float* fa      = ws + WS_FA;
    float* ka      = ws + WS_KA;
    float* sp      = ws + WS_SP;
    float* partial = ws + WS_PART;
    unsigned short* w2t = (unsigned short*)(ws + WS_W2T);
    unsigned short* xt  = (unsigned short*)(ws + WS_XT);

    transpose_pool<<<dim3(HH, NB), 256, 0, stream>>>(x, xt, partial, zeros);
    attn3<<<1, 512, 0, stream>>>(partial, prep_w, bn_g, bn_b, bn_m, bn_v,
                                 fc_sp_w, fc_sp_b, fc_ch_w, fc_ch_b,
                                 fc_f_w, fc_f_b, fc_k_w, fc_k_b,
                                 sp, cha, fa, ka);
    w2t2<<<NB * 16, 256, 0, stream>>>(kernels, sp, cha, fa, ka, w2t);
    conv_lds<<<2048, 512, 0, stream>>>(xt, w2t, (const unsigned short*)zeros, out);
}

// Round 7
// 173.169 us; speedup vs baseline: 1.2126x; 1.1856x over previous
//
#include <hip/hip_runtime.h>
#include <math.h>

// Problem constants
#define NB 32
#define CI 64
#define CO 64
#define CA 16
#define NK 4
#define HH 128
#define WW 128
#define EPSBN 1e-5f

typedef __bf16 bf16x8 __attribute__((ext_vector_type(8)));
typedef float f32x4 __attribute__((ext_vector_type(4)));

__device__ inline unsigned short f2bf(float f) {
    union { float f; unsigned u; } c; c.f = f;
    return (unsigned short)((c.u + 0x7fffu + ((c.u >> 16) & 1u)) >> 16);
}

__device__ inline void gload_lds16(const void* g, void* l) {
    __builtin_amdgcn_global_load_lds(
        (const __attribute__((address_space(1))) unsigned int*)g,
        (__attribute__((address_space(3))) unsigned int*)l, 16, 0, 0);
}

// Workspace layout (float offsets). Total 70.5 MB (proven available in r4+).
#define WS_ZERO  0              // 64 (zero page for OOB redirect)
#define WS_CHA   64             // 2048
#define WS_FA    2112           // 2048
#define WS_KA    4160           // 128
#define WS_SP    4288           // 288
#define WS_PART  8192           // 32*64*32 = 65536 used
#define WS_W2T   270336         // 1179648 ushorts
#define WS_XT    860160         // 33554432 ushorts

// ===========================================================================
// 1) Register transpose + pooled partials. Block = (hg of 4 rows, b), 256 thr
//    = 4 waves (ci-half x w-half). Lane owns one w, all 32 ci of its half:
//    reads coalesced 256B/instr, packs bf16, stores 64B/lane NHWC. Pool sums
//    accumulate in registers across the 4 rows; ONE LDS reduce per block.
// ===========================================================================
__global__ __launch_bounds__(256) void transpose_pool(const float* __restrict__ x,
                                                      unsigned short* __restrict__ xt,
                                                      float* __restrict__ partial,
                                                      float* __restrict__ zeros) {
    __shared__ float vs[64 * 129];
    __shared__ float red[64 * 4];
    const int tid = threadIdx.x;
    const int hg = blockIdx.x;       // 0..31
    const int b  = blockIdx.y;
    const int lane = tid & 63;
    const int wv  = tid >> 6;
    const int cih = wv & 1;
    const int wh  = wv >> 1;
    const int w = wh * 64 + lane;

    if (hg == 0 && b == 0 && tid < 64) zeros[tid] = 0.f;   // zero page for conv

    float sum[32];
    #pragma unroll
    for (int i = 0; i < 32; ++i) sum[i] = 0.f;

    #pragma unroll 1
    for (int r = 0; r < 4; ++r) {
        const int h = hg * 4 + r;
        const float* xp = x + ((size_t)(b * CI + cih * 32) * HH + h) * WW + w;
        float vals[32];
        #pragma unroll
        for (int i = 0; i < 32; ++i) vals[i] = xp[(size_t)i * (HH * WW)];
        #pragma unroll
        for (int i = 0; i < 32; ++i) sum[i] += vals[i];
        unsigned q[16];
        #pragma unroll
        for (int i = 0; i < 16; ++i)
            q[i] = (unsigned)f2bf(vals[2 * i]) | ((unsigned)f2bf(vals[2 * i + 1]) << 16);
        unsigned short* dst = xt + ((size_t)(b * HH + h) * WW + w) * CI + cih * 32;
        #pragma unroll
        for (int j = 0; j < 4; ++j)
            ((uint4*)dst)[j] = make_uint4(q[4 * j], q[4 * j + 1], q[4 * j + 2], q[4 * j + 3]);
    }

    #pragma unroll
    for (int i = 0; i < 32; ++i) vs[(cih * 32 + i) * 129 + w] = sum[i];
    __syncthreads();
    {
        const int ci = tid & 63, qd = tid >> 6;
        float s = 0.f;
        #pragma unroll
        for (int e = 0; e < 32; ++e) s += vs[ci * 129 + qd * 32 + e];
        red[ci * 4 + qd] = s;
    }
    __syncthreads();
    if (tid < 64)
        partial[((size_t)b * CI + tid) * 32 + hg] =
            red[tid * 4] + red[tid * 4 + 1] + red[tid * 4 + 2] + red[tid * 4 + 3];
}

// ===========================================================================
// 2) attention: reduce partials (32 hg, contiguous) + trunk + 4 heads.
// ===========================================================================
__global__ __launch_bounds__(512) void attn3(
    const float* __restrict__ partial, const float* __restrict__ prep_w,
    const float* __restrict__ bn_g, const float* __restrict__ bn_b,
    const float* __restrict__ bn_m, const float* __restrict__ bn_v,
    const float* __restrict__ fc_sp_w, const float* __restrict__ fc_sp_b,
    const float* __restrict__ fc_ch_w, const float* __restrict__ fc_ch_b,
    const float* __restrict__ fc_f_w,  const float* __restrict__ fc_f_b,
    const float* __restrict__ fc_k_w,  const float* __restrict__ fc_k_b,
    float* __restrict__ sp, float* __restrict__ cha,
    float* __restrict__ fa, float* __restrict__ ka) {
    __shared__ float pooled_s[NB * CI];
    __shared__ float att_s[NB * CA];
    const int tid = threadIdx.x;
    const float scale = 1.f / (HH * WW);
    #pragma unroll
    for (int i = 0; i < 4; ++i) {
        const int e = tid + 512 * i;
        const float4* pp = (const float4*)(partial + (size_t)e * 32);
        float s = 0.f;
        #pragma unroll
        for (int j = 0; j < 8; ++j) { float4 v = pp[j]; s += v.x + v.y + v.z + v.w; }
        pooled_s[e] = s;
    }
    __syncthreads();
    const int b = tid >> 4, a = tid & 15;
    {
        float s = 0.f;
        const float* pv = pooled_s + b * CI;
        #pragma unroll
        for (int c = 0; c < CI; ++c) s += pv[c] * prep_w[a * CI + c];
        s = (s * scale - bn_m[a]) * rsqrtf(bn_v[a] + EPSBN) * bn_g[a] + bn_b[a];
        att_s[b * CA + a] = fmaxf(s, 0.f);
    }
    __syncthreads();
    float av[CA];
    #pragma unroll
    for (int i = 0; i < CA; ++i) av[i] = att_s[b * CA + i];

    const int j = a;
    if (j < 9) {
        float s = fc_sp_b[j];
        #pragma unroll
        for (int i = 0; i < CA; ++i) s += av[i] * fc_sp_w[j * CA + i];
        sp[b * 9 + j] = 1.f / (1.f + expf(-s));
    }
    #pragma unroll
    for (int t = 0; t < 4; ++t) {
        const int c = j * 4 + t;
        float s1 = fc_ch_b[c], s2 = fc_f_b[c];
        #pragma unroll
        for (int i = 0; i < CA; ++i) {
            s1 += av[i] * fc_ch_w[c * CA + i];
            s2 += av[i] * fc_f_w[c * CA + i];
        }
        cha[b * CI + c] = 1.f / (1.f + expf(-s1));
        fa[b * CO + c]  = 1.f / (1.f + expf(-s2));
    }
    if (j == 0) {
        float kv[NK], m = -1e30f;
        #pragma unroll
        for (int k = 0; k < NK; ++k) {
            float s = fc_k_b[k];
            #pragma unroll
            for (int i = 0; i < CA; ++i) s += av[i] * fc_k_w[k * CA + i];
            kv[k] = s; m = fmaxf(m, s);
        }
        float den = 0.f;
        #pragma unroll
        for (int k = 0; k < NK; ++k) { kv[k] = expf(kv[k] - m); den += kv[k]; }
        #pragma unroll
        for (int k = 0; k < NK; ++k) ka[b * NK + k] = kv[k] / den;
    }
}

// ===========================================================================
// 3) folded weights w2t[b][tap][o][i] bf16 (lanes = i: 128B-line writes)
// ===========================================================================
__global__ __launch_bounds__(256) void w2t2(const float* __restrict__ kernels,
                                            const float* __restrict__ sp,
                                            const float* __restrict__ cha,
                                            const float* __restrict__ fa,
                                            const float* __restrict__ ka,
                                            unsigned short* __restrict__ w2t) {
    const int bid = blockIdx.x;              // 32*16
    const int b  = bid >> 4;
    const int o  = (bid & 15) * 4 + (threadIdx.x >> 6);
    const int i  = threadIdx.x & 63;
    float kw[NK][9];
    #pragma unroll
    for (int k = 0; k < NK; ++k) {
        const float* kp = kernels + ((size_t)(k * CO + o) * CI + i) * 9;
        #pragma unroll
        for (int t = 0; t < 9; ++t) kw[k][t] = kp[t];
    }
    float kav[NK];
    #pragma unroll
    for (int k = 0; k < NK; ++k) kav[k] = ka[b * NK + k];
    const float base = cha[b * CI + i] * fa[b * CO + o];
    #pragma unroll
    for (int tap = 0; tap < 9; ++tap) {
        float s = 0.f;
        #pragma unroll
        for (int k = 0; k < NK; ++k) s += kav[k] * kw[k][tap];
        w2t[((size_t)(b * 9 + tap) * CO + o) * CI + i] = f2bf(s * sp[b * 9 + tap] * base);
    }
}

// ===========================================================================
// 4) LDS-staged conv (mfma_f32_16x16x32_bf16), software-pipelined A-loads.
//    Block = 64co x 64col x 4row, 512 thr = 8 waves (cohalf x colq).
//    x tile staged once via global_load_lds (zero-page redirect, oct-XOR
//    swizzle baked into the source address). Compute: idx=0..5 over (ks,v),
//    A-fragments for idx+1 issued BEFORE the 24 MFMAs of idx (latency hidden
//    under MFMA execution instead of exposed per-u).
// ===========================================================================
__global__ __launch_bounds__(512, 4) void conv_lds(const unsigned short* __restrict__ xt,
                                                   const unsigned short* __restrict__ w2t,
                                                   const unsigned short* __restrict__ zeros,
                                                   float* __restrict__ out) {
    __shared__ __align__(16) unsigned char xs[51200];   // 50 chunks x 1024B
    const int tid  = threadIdx.x;
    const int lane = tid & 63;
    const int wv   = tid >> 6;
    const int orig = blockIdx.x;
    const int bid  = (orig & 7) * 256 + (orig >> 3);    // XCD swizzle (bijective)
    const int b   = bid >> 6;
    const int rem = bid & 63;
    const int hg  = rem >> 1;
    const int cg2 = rem & 1;
    const int h0 = hg * 4;
    const int w0 = cg2 * 64;

    const unsigned short* xb = xt + (size_t)b * (HH * WW * CI);

    // ---- stage: 3168 16B-units (+pad), all loads in flight before barrier
    for (int chunk = wv; chunk < 50; chunk += 8) {
        const int unit = (chunk << 6) + lane;
        const int row  = (int)((unsigned)unit / 528u);
        const int rr   = unit - row * 528;
        const int col  = rr >> 3;
        const int q    = rr & 7;
        const int hh = h0 - 1 + row;
        const int wc = w0 - 1 + col;
        const unsigned short* g = zeros;
        if (unit < 3168 && (unsigned)hh < (unsigned)HH && (unsigned)wc < (unsigned)WW)
            g = xb + (((size_t)hh << 7) + (size_t)wc) * 64 + ((q ^ (col & 7)) << 3);
        gload_lds16(g, xs + (chunk << 10));
    }
    __syncthreads();

    const int cl = lane & 15;        // pixel col in 16 / o in 16
    const int kq = lane >> 4;        // k-quarter (8 ci)
    const int cohalf = wv & 1;
    const int colq   = wv >> 1;      // 0..3

    const unsigned short* w2b = w2t + (size_t)b * (9 * 4096)
                              + (size_t)(cohalf * 32) * 64 + kq * 8;

    f32x4 acc[2][4];
    #pragma unroll
    for (int og = 0; og < 2; ++og)
        #pragma unroll
        for (int t = 0; t < 4; ++t)
            #pragma unroll
            for (int e = 0; e < 4; ++e) acc[og][t][e] = 0.f;

    // A-fragment address for (idx: ks=idx/3, v=idx%3), u, og
    auto aptr = [&](int idx, int u, int og) -> const bf16x8* {
        const int ks = idx / 3, v = idx - ks * 3;
        return (const bf16x8*)(w2b + (size_t)(u * 3 + v) * 4096 + ks * 32 + (og * 16 + cl) * 64);
    };

    bf16x8 Acur[3][2], Anext[3][2];
    #pragma unroll
    for (int u = 0; u < 3; ++u)
        #pragma unroll
        for (int og = 0; og < 2; ++og) Acur[u][og] = *aptr(0, u, og);

    #pragma unroll
    for (int idx = 0; idx < 6; ++idx) {
        const int ks = idx / 3, v = idx - ks * 3;
        // prefetch A for idx+1 (in flight during this idx's MFMAs)
        if (idx < 5) {
            #pragma unroll
            for (int u = 0; u < 3; ++u)
                #pragma unroll
                for (int og = 0; og < 2; ++og) Anext[u][og] = *aptr(idx + 1, u, og);
        }
        // B fragments: 6 rows, reused across the 3 u-taps
        const int lcol = colq * 16 + cl + v;            // LDS col 0..65
        const int sw = ((ks << 2) + kq) ^ (lcol & 7);   // swizzled oct slot
        const unsigned char* bp = xs + (((lcol << 3) + sw) << 4);
        bf16x8 Bf[6];
        #pragma unroll
        for (int r = 0; r < 6; ++r)
            Bf[r] = *(const bf16x8*)(bp + r * 8448);
        #pragma unroll
        for (int u = 0; u < 3; ++u)
            #pragma unroll
            for (int og = 0; og < 2; ++og)
                #pragma unroll
                for (int t = 0; t < 4; ++t)
                    acc[og][t] = __builtin_amdgcn_mfma_f32_16x16x32_bf16(
                        Acur[u][og], Bf[t + u], acc[og][t], 0, 0, 0);
        #pragma unroll
        for (int u = 0; u < 3; ++u)
            #pragma unroll
            for (int og = 0; og < 2; ++og) Acur[u][og] = Anext[u][og];
    }

    // ---- epilogue: C/D row (co-in-16) = kq*4 + rg, col = cl
    #pragma unroll
    for (int og = 0; og < 2; ++og)
        #pragma unroll
        for (int t = 0; t < 4; ++t) {
            float* op = out + ((size_t)(b * CO + cohalf * 32 + og * 16 + kq * 4) * HH + h0 + t) * WW
                      + w0 + colq * 16 + cl;
            #pragma unroll
            for (int rg = 0; rg < 4; ++rg)
                op[(size_t)rg * (HH * WW)] = acc[og][t][rg];
        }
}

// ===========================================================================
extern "C" void kernel_launch(void* const* d_in, const int* in_sizes, int n_in,
                              void* d_out, int out_size, void* d_ws, size_t ws_size,
                              hipStream_t stream) {
    const float* x        = (const float*)d_in[0];
    const float* prep_w   = (const float*)d_in[1];
    const float* bn_g     = (const float*)d_in[2];
    const float* bn_b     = (const float*)d_in[3];
    const float* bn_m     = (const float*)d_in[4];
    const float* bn_v     = (const float*)d_in[5];
    const float* fc_sp_w  = (const float*)d_in[6];
    const float* fc_sp_b  = (const float*)d_in[7];
    const float* fc_ch_w  = (const float*)d_in[8];
    const float* fc_ch_b  = (const float*)d_in[9];
    const float* fc_f_w   = (const float*)d_in[10];
    const float* fc_f_b   = (const float*)d_in[11];
    const float* fc_k_w   = (const float*)d_in[12];
    const float* fc_k_b   = (const float*)d_in[13];
    const float* kernels  = (const float*)d_in[14];
    float* out = (float*)d_out;
    float* ws  = (float*)d_ws;

    float* zeros   = ws + WS_ZERO;
    float* cha     = ws + WS_CHA;
    float* fa      = ws + WS_FA;
    float* ka      = ws + WS_KA;
    float* sp      = ws + WS_SP;
    float* partial = ws + WS_PART;
    unsigned short* w2t = (unsigned short*)(ws + WS_W2T);
    unsigned short* xt  = (unsigned short*)(ws + WS_XT);

    transpose_pool<<<dim3(32, NB), 256, 0, stream>>>(x, xt, partial, zeros);
    attn3<<<1, 512, 0, stream>>>(partial, prep_w, bn_g, bn_b, bn_m, bn_v,
                                 fc_sp_w, fc_sp_b, fc_ch_w, fc_ch_b,
                                 fc_f_w, fc_f_b, fc_k_w, fc_k_b,
                                 sp, cha, fa, ka);
    w2t2<<<NB * 16, 256, 0, stream>>>(kernels, sp, cha, fa, ka, w2t);
    conv_lds<<<2048, 512, 0, stream>>>(xt, w2t, (const unsigned short*)zeros, out);
}